// Round 8
// baseline (131.626 us; speedup 1.0000x reference)
//
#include <hip/hip_runtime.h>

typedef _Float16 f16;
typedef f16 f16x8 __attribute__((ext_vector_type(8)));
typedef f16 f16x4 __attribute__((ext_vector_type(4)));
typedef float f32x4 __attribute__((ext_vector_type(4)));

// ---------------------------------------------------------------------------
// Prep:
//   s_bf[n][u]      = f16(node_vec[n][u])            (8192 x 128)
//   W1G[w*32+v][u]  = f16(W1s[u][v][w])              (4096 x 128)
//   W2G[w2*32+v][u] = f16(W2[u][v][w2])              (1024 x 128)
// ---------------------------------------------------------------------------
__global__ __launch_bounds__(256) void prep_kernel(
    const float* __restrict__ node_vec, const float* __restrict__ W1s,
    const float* __restrict__ W2, f16* __restrict__ s_bf,
    f16* __restrict__ W1G, f16* __restrict__ W2G)
{
    const int b = blockIdx.x, t = threadIdx.x;
    if (b < 512) {
        int j = b * 256 + t;
        int n = j >> 4, c8 = (j & 15) * 8;
        float4 a = *(const float4*)(node_vec + (size_t)n * 480 + c8);
        float4 c = *(const float4*)(node_vec + (size_t)n * 480 + c8 + 4);
        f16x8 o = { (f16)a.x, (f16)a.y, (f16)a.z, (f16)a.w,
                    (f16)c.x, (f16)c.y, (f16)c.z, (f16)c.w };
        *(f16x8*)(s_bf + (size_t)n * 128 + c8) = o;
    } else if (b < 1024) {
        int bb = b - 512;
        int cb = bb >> 2, u0 = (bb & 3) * 32;     // w = cb (c-tile), u-tile
        int v = t >> 3, u = u0 + (t & 7) * 4;
        f16x4 o = { (f16)W1s[(size_t)(u + 0) * 4096 + v * 128 + cb],
                    (f16)W1s[(size_t)(u + 1) * 4096 + v * 128 + cb],
                    (f16)W1s[(size_t)(u + 2) * 4096 + v * 128 + cb],
                    (f16)W1s[(size_t)(u + 3) * 4096 + v * 128 + cb] };
        *(f16x4*)(W1G + (size_t)(32 * cb + v) * 128 + u) = o;
    } else {
        int bb = b - 1024;
        int cb = bb >> 2, u0 = (bb & 3) * 32;     // w2 = cb
        int v = t >> 3, u = u0 + (t & 7) * 4;
        f16x4 o = { (f16)W2[(size_t)(u + 0) * 1024 + v * 32 + cb],
                    (f16)W2[(size_t)(u + 1) * 1024 + v * 32 + cb],
                    (f16)W2[(size_t)(u + 2) * 1024 + v * 32 + cb],
                    (f16)W2[(size_t)(u + 3) * 1024 + v * 32 + cb] };
        *(f16x4*)(W2G + (size_t)(32 * cb + v) * 128 + u) = o;
    }
}

// ---------------------------------------------------------------------------
// G-form GEMM + in-register v-contraction.
//   G[n,c] = sum_u A[n,u] * B[c,u]   (tile 128x128, K=128, LDS-staged A,B)
//   out[n,w] = f( sum_v attr[n,v] * G[n,32w+v] / 64 + bias[w] )
// Wave wv owns rows 32wv..+32 (2 m-tiles) x all 128 cols (8 c-tiles).
// Epilogue: scale each C element by attr[row][v] (v = 16*(ct&1)+lr), pair
// the two c-tiles of each w, butterfly-reduce over the 16 lr lanes.
// SILU=1: silu -> f16 out [n][128]; SILU=0: identity -> f32 out [n][32].
// ---------------------------------------------------------------------------
template <int SILU>
__global__ __launch_bounds__(256, 2) void gemm_g(
    const f16* __restrict__ A, const f16* __restrict__ B,
    const float* __restrict__ attr, const float* __restrict__ bias,
    void* __restrict__ out)
{
    __shared__ __align__(16) unsigned char smem[69632];
    f16* A_lds = (f16*)smem;               // [128][136]
    f16* B_lds = (f16*)smem + 128 * 136;   // [128][136]

    const int t  = threadIdx.x;
    const int n0 = blockIdx.x * 128;
    const int c0 = blockIdx.y * 128;

    // stage A and B tiles (32 KB each, coalesced 16B/lane)
    #pragma unroll
    for (int i = 0; i < 8; ++i) {
        int idx = t + 256 * i;
        int r = idx >> 4, c8 = (idx & 15) * 8;
        *(uint4*)(A_lds + r * 136 + c8) = *(const uint4*)(A + (size_t)(n0 + r) * 128 + c8);
        *(uint4*)(B_lds + r * 136 + c8) = *(const uint4*)(B + (size_t)(c0 + r) * 128 + c8);
    }
    __syncthreads();

    const int wv = t >> 6, l = t & 63, lr = l & 15, q = l >> 4;
    const int r0 = 32 * wv;

    f32x4 acc0[8], acc1[8];
    #pragma unroll
    for (int ct = 0; ct < 8; ++ct) { acc0[ct] = f32x4{0,0,0,0}; acc1[ct] = f32x4{0,0,0,0}; }

    #pragma unroll
    for (int ks = 0; ks < 4; ++ks) {
        f16x8 a0 = *(const f16x8*)(A_lds + (r0 + lr) * 136 + ks * 32 + q * 8);
        f16x8 a1 = *(const f16x8*)(A_lds + (r0 + 16 + lr) * 136 + ks * 32 + q * 8);
        #pragma unroll
        for (int ct = 0; ct < 8; ++ct) {
            f16x8 bf = *(const f16x8*)(B_lds + (16 * ct + lr) * 136 + ks * 32 + q * 8);
            acc0[ct] = __builtin_amdgcn_mfma_f32_16x16x32_f16(a0, bf, acc0[ct], 0, 0, 0);
            acc1[ct] = __builtin_amdgcn_mfma_f32_16x16x32_f16(a1, bf, acc1[ct], 0, 0, 0);
        }
    }

    // attr factors: at[mt][reg][p], p=0 -> v=lr, p=1 -> v=16+lr (L2-hit loads)
    float at[2][4][2];
    #pragma unroll
    for (int mt = 0; mt < 2; ++mt)
        #pragma unroll
        for (int reg = 0; reg < 4; ++reg) {
            int row = n0 + r0 + 16 * mt + q * 4 + reg;
            at[mt][reg][0] = attr[(size_t)row * 32 + lr];
            at[mt][reg][1] = attr[(size_t)row * 32 + 16 + lr];
        }

    // contraction: for each (mt, w): pv[reg] = sum over both c-tiles, then
    // butterfly over the 16 lr lanes (masks 1,2,4,8 stay within the group)
    #pragma unroll
    for (int mt = 0; mt < 2; ++mt)
        #pragma unroll
        for (int w = 0; w < 4; ++w) {
            f32x4 e0 = mt ? acc1[2 * w] : acc0[2 * w];
            f32x4 e1 = mt ? acc1[2 * w + 1] : acc0[2 * w + 1];
            float pv[4];
            #pragma unroll
            for (int reg = 0; reg < 4; ++reg)
                pv[reg] = e0[reg] * at[mt][reg][0] + e1[reg] * at[mt][reg][1];
            #pragma unroll
            for (int m = 1; m <= 8; m <<= 1) {
                #pragma unroll
                for (int reg = 0; reg < 4; ++reg)
                    pv[reg] += __shfl_xor(pv[reg], m);
            }
            if (lr == 0) {
                int wglob = (c0 >> 5) + w;
                float bv = bias[wglob];
                #pragma unroll
                for (int reg = 0; reg < 4; ++reg) {
                    int row = n0 + r0 + 16 * mt + q * 4 + reg;
                    float val = pv[reg] * 0.015625f + bv;
                    if (SILU) {
                        ((f16*)out)[(size_t)row * 128 + wglob] =
                            (f16)(val / (1.f + __expf(-val)));
                    } else {
                        ((float*)out)[(size_t)row * 32 + wglob] = val;
                    }
                }
            }
        }
}

// ---------------------------------------------------------------------------
// Head: out[n] = silu(h @ W3/sqrt(32) + b3) @ W4/sqrt(32) + b4
// ---------------------------------------------------------------------------
__global__ __launch_bounds__(256) void head_kernel(
    const float* __restrict__ h, const float* __restrict__ W3,
    const float* __restrict__ b3, const float* __restrict__ W4,
    const float* __restrict__ b4, float* __restrict__ out)
{
    int tid = blockIdx.x * 256 + threadIdx.x;
    int n = tid >> 5, j = tid & 31;
    const float inv = 0.17677669529663687f;  // 1/sqrt(32)
    const float* hr = h + (size_t)n * 32;
    float acc = 0.f;
    #pragma unroll
    for (int i = 0; i < 32; ++i) acc += hr[i] * W3[i * 32 + j];
    float tv = acc * inv + b3[j];
    float g  = tv / (1.f + __expf(-tv));
    float p  = g * W4[j] * inv;
    #pragma unroll
    for (int m = 16; m >= 1; m >>= 1) p += __shfl_xor(p, m, 32);
    if (j == 0) out[n] = p + b4[0];
}

// ---------------------------------------------------------------------------
extern "C" void kernel_launch(void* const* d_in, const int* in_sizes, int n_in,
                              void* d_out, int out_size, void* d_ws, size_t ws_size,
                              hipStream_t stream)
{
    const float* node_vec = (const float*)d_in[0];
    const float* attr     = (const float*)d_in[1];
    const float* W1s      = (const float*)d_in[2];
    const float* b1s      = (const float*)d_in[3];
    // d_in[4..7] (W1g,b1g,W1v1,W1v2) are dead code w.r.t. pred_energy
    const float* W2       = (const float*)d_in[8];
    const float* b2       = (const float*)d_in[9];
    const float* W3       = (const float*)d_in[10];
    const float* b3       = (const float*)d_in[11];
    const float* W4       = (const float*)d_in[12];
    const float* b4       = (const float*)d_in[13];
    float* out = (float*)d_out;

    char* ws = (char*)d_ws;
    f16*   s_bf  = (f16*)(ws);                     // 8192*128*2 = 2 MiB
    f16*   W1G   = (f16*)(ws + (2048u << 10));     // 4096*128*2 = 1 MiB
    f16*   W2G   = (f16*)(ws + (3072u << 10));     // 1024*128*2 = 256 KiB
    f16*   s_act = (f16*)(ws + (3328u << 10));     // 8192*128*2 = 2 MiB
    float* h     = (float*)(ws + (5376u << 10));   // 8192*32*4  = 1 MiB

    prep_kernel<<<1152, 256, 0, stream>>>(node_vec, W1s, W2, s_bf, W1G, W2G);
    gemm_g<1><<<dim3(64, 32), 256, 0, stream>>>(s_bf, W1G, attr, b1s, (void*)s_act);
    gemm_g<0><<<dim3(64, 8),  256, 0, stream>>>(s_act, W2G, attr, b2, (void*)h);
    head_kernel<<<1024, 256, 0, stream>>>(h, W3, b3, W4, b4, out);
}